// Round 8
// baseline (119.657 us; speedup 1.0000x reference)
//
#include <hip/hip_runtime.h>
#include <hip/hip_bf16.h>

#define NB 2
#define NN 30
#define NC 320
#define NM 31
#define HW 4096
#define FMIN_F (-3.40282346638528859812e+38f)
#define PCH 8                  // pixel chunks per (b,m) in fw

typedef float nfloat4 __attribute__((ext_vector_type(4)));

// workspace layout (float offsets)
#define OFF_FSUM   0         // [2*4096]  sum_c nhs
#define OFF_FWRED  8192      // [2*4096]  sum_c nhs*w_reduce
#define OFF_ASUM   16384     // [2*4096]  sum_c attn
#define OFF_AWRED  24576     // [2*4096]  sum_c attn*w_reduce
#define OFF_Z      32768     // [62*4096] fw with -FLT_MAX sentinel where fg=false
#define OFF_MP     286720    // [64] per-(b,m) max of raw fw (monotone-uint encoded)
#define WS_FLOATS  286784
// byte offsets past the float region:
#define ROIF_BYTE  1147136               // roi_feats bf16: 2*30*1024*320*2 = 39321600 B
#define NHSBF_BYTE (ROIF_BYTE + 39321600) // bf16 copy of nhs image: 2*4096*320*2 = 5242880 B

#define GRID_ROIF (NB * NN * 128)      // 8 cells/block -> 7680
#define GRID_FW   (NB * NM * PCH)      // 496
#define GRID_RED  1639                 // ceil(8192/5)

__device__ __forceinline__ void get_box(const float* boxes, int b, int n,
                                        float& x1, float& y1, float& bw, float& bh) {
    const float* p = boxes + (b * NN + n) * 4;
    float X1 = p[0] * 64.0f - 0.5f;
    float Y1 = p[1] * 64.0f - 0.5f;
    float X2 = p[2] * 64.0f - 0.5f;
    float Y2 = p[3] * 64.0f - 0.5f;
    x1 = X1; y1 = Y1;
    bw = (X2 - X1) / 32.0f;
    bh = (Y2 - Y1) / 32.0f;
}

__device__ __forceinline__ unsigned short f2bf(float f) {
    __hip_bfloat16 h = __float2bfloat16(f);
    return *reinterpret_cast<unsigned short*>(&h);
}
__device__ __forceinline__ unsigned pack2(float a, float b) {
    return (unsigned)f2bf(a) | ((unsigned)f2bf(b) << 16);
}
__device__ __forceinline__ float blo(unsigned u) { return __uint_as_float(u << 16); }
__device__ __forceinline__ float bhi(unsigned u) { return __uint_as_float(u & 0xffff0000u); }

// monotone float <-> uint encoding for atomicMax over signed floats
__device__ __forceinline__ unsigned encf(float f) {
    unsigned u = __float_as_uint(f);
    return (u & 0x80000000u) ? ~u : (u | 0x80000000u);
}
__device__ __forceinline__ float decf(unsigned e) {
    unsigned u = (e & 0x80000000u) ? (e & 0x7fffffffu) : ~e;
    return __uint_as_float(u);
}

// Kernel 1: per-pixel channel reductions + packed-bf16 copy of nhs.
// one wave per row (5 rows/block at 320 threads).
__global__ void k_pre(const float* __restrict__ nhs, const float* __restrict__ attn,
                      const float* __restrict__ wred, float* __restrict__ ws,
                      unsigned* __restrict__ nbf) {
    if (blockIdx.x == 0 && threadIdx.x < 64)
        ((unsigned*)(ws + OFF_MP))[threadIdx.x] = 0u;
    int wave = threadIdx.x >> 6;
    int lane = threadIdx.x & 63;
    int row = blockIdx.x * 5 + wave;
    if (row >= NB * HW) return;
    const float4* n4 = (const float4*)(nhs + (size_t)row * NC);
    const float4* a4 = (const float4*)(attn + (size_t)row * NC);
    const float4* w4 = (const float4*)wred;
    float4 wv = w4[lane];
    float4 nv = n4[lane];
    float4 av = a4[lane];
    // bf16 copy: lane l holds ch 4l..4l+3 -> uint2 at row*80 + l
    uint2 pk0; pk0.x = pack2(nv.x, nv.y); pk0.y = pack2(nv.z, nv.w);
    ((uint2*)nbf)[(size_t)row * 80 + lane] = pk0;
    float s_n = nv.x + nv.y + nv.z + nv.w;
    float w_n = nv.x * wv.x + nv.y * wv.y + nv.z * wv.z + nv.w * wv.w;
    float s_a = av.x + av.y + av.z + av.w;
    float w_a = av.x * wv.x + av.y * wv.y + av.z * wv.z + av.w * wv.w;
    if (lane < 16) {                   // second chunk: float4 index 64..79
        float4 wv2 = w4[lane + 64];
        float4 nv2 = n4[lane + 64];
        float4 av2 = a4[lane + 64];
        uint2 pk1; pk1.x = pack2(nv2.x, nv2.y); pk1.y = pack2(nv2.z, nv2.w);
        ((uint2*)nbf)[(size_t)row * 80 + 64 + lane] = pk1;
        s_n += nv2.x + nv2.y + nv2.z + nv2.w;
        w_n += nv2.x * wv2.x + nv2.y * wv2.y + nv2.z * wv2.z + nv2.w * wv2.w;
        s_a += av2.x + av2.y + av2.z + av2.w;
        w_a += av2.x * wv2.x + av2.y * wv2.y + av2.z * wv2.z + av2.w * wv2.w;
    }
#pragma unroll
    for (int off = 32; off > 0; off >>= 1) {
        s_n += __shfl_down(s_n, off, 64);
        w_n += __shfl_down(w_n, off, 64);
        s_a += __shfl_down(s_a, off, 64);
        w_a += __shfl_down(w_a, off, 64);
    }
    if (lane == 0) {
        ws[OFF_FSUM + row]  = s_n;
        ws[OFF_FWRED + row] = w_n;
        ws[OFF_ASUM + row]  = s_a;
        ws[OFF_AWRED + row] = w_a;
    }
}

// ---- part A of k_stage2: roi_feats gather from bf16 image ----
// block = 8 cells x 40 lanes; thread = 8 channels (one uint4 per tap).
__device__ void do_roifeat(int blk, const unsigned* __restrict__ nbf,
                           const float* __restrict__ boxes,
                           const int* __restrict__ masks,
                           unsigned* __restrict__ roif,
                           float* wsm /*[8][9]*/, int* bsm /*[8]*/) {
    int bn = blk >> 7;                 // 8 cells/block, 128 blocks per (b,n)
    int n = bn % NN;
    int b = bn / NN;
    if (masks[b * NN + n] == 0) return;
    int tid = threadIdx.x;
    float x1, y1, bw, bh;
    get_box(boxes, b, n, x1, y1, bw, bh);

    if (tid < 8) {
        int cell = blk * 8 + tid;
        int q = cell & 31;
        int p = (cell >> 5) & 31;
        float W[9] = {0.f,0.f,0.f,0.f,0.f,0.f,0.f,0.f,0.f};
        float wys[4], wxs[4];
        int iy0s[4], ix0s[4];
        int iymin = 64, ixmin = 64;
#pragma unroll
        for (int s_ = 0; s_ < 4; s_++) {
            int di = s_ >> 1, dj = s_ & 1;
            float y = y1 + ((float)p + 0.25f + 0.5f * (float)di) * bh;
            float x = x1 + ((float)q + 0.25f + 0.5f * (float)dj) * bw;
            float yc = fminf(fmaxf(y, 0.0f), 63.0f);
            float xc = fminf(fmaxf(x, 0.0f), 63.0f);
            int iy0 = (int)floorf(yc), ix0 = (int)floorf(xc);
            wys[s_] = yc - (float)iy0;
            wxs[s_] = xc - (float)ix0;
            iy0s[s_] = iy0; ix0s[s_] = ix0;
            iymin = min(iymin, iy0); ixmin = min(ixmin, ix0);
        }
#pragma unroll
        for (int s_ = 0; s_ < 4; s_++) {
            float wy = wys[s_], wx = wxs[s_];
            int dy = iy0s[s_] - iymin;
            int dx = ix0s[s_] - ixmin;
            bool yt = (iy0s[s_] == 63);
            bool xt = (ix0s[s_] == 63);
            float ay0 = yt ? 1.0f : (1.0f - wy);
            float ay1 = yt ? 0.0f : wy;
            float ax0 = xt ? 1.0f : (1.0f - wx);
            float ax1 = xt ? 0.0f : wx;
            float r0 = dy ? 0.0f : ay0;
            float r1 = dy ? ay0  : ay1;
            float r2 = dy ? ay1  : 0.0f;
            float c0 = dx ? 0.0f : ax0;
            float c1 = dx ? ax0  : ax1;
            float c2 = dx ? ax1  : 0.0f;
            W[0] += r0 * c0; W[1] += r0 * c1; W[2] += r0 * c2;
            W[3] += r1 * c0; W[4] += r1 * c1; W[5] += r1 * c2;
            W[6] += r2 * c0; W[7] += r2 * c1; W[8] += r2 * c2;
        }
#pragma unroll
        for (int k = 0; k < 9; k++) wsm[tid * 9 + k] = W[k] * 0.25f;
        bsm[tid] = iymin * 64 + ixmin;
    }
    __syncthreads();

    int cid = tid / 40;
    int v = tid - cid * 40;            // 8-channel group
    int cell = blk * 8 + cid;
    const uint4* fb = (const uint4*)nbf;   // row r: 40 uint4 starting at r*40
    size_t brow = (size_t)b * HW;
    int base = bsm[cid];
    float4 acc0 = make_float4(0.f, 0.f, 0.f, 0.f);
    float4 acc1 = make_float4(0.f, 0.f, 0.f, 0.f);
#pragma unroll
    for (int i = 0; i < 3; i++) {
#pragma unroll
        for (int j = 0; j < 3; j++) {
            float w = wsm[cid * 9 + i * 3 + j];
            if (w != 0.0f) {
                uint4 U = fb[(brow + base + i * 64 + j) * 40 + v];
                acc0.x += w * blo(U.x); acc0.y += w * bhi(U.x);
                acc0.z += w * blo(U.y); acc0.w += w * bhi(U.y);
                acc1.x += w * blo(U.z); acc1.y += w * bhi(U.z);
                acc1.z += w * blo(U.w); acc1.w += w * bhi(U.w);
            }
        }
    }
    uint4 pk;
    pk.x = pack2(acc0.x, acc0.y);
    pk.y = pack2(acc0.z, acc0.w);
    pk.z = pack2(acc1.x, acc1.y);
    pk.w = pack2(acc1.z, acc1.w);
    ((uint4*)roif)[(size_t)cell * 40 + v] = pk;
}

// ---- part B of k_stage2: fused roi_sums + fw, chunked ----
__device__ void do_fw(int unit, const float* __restrict__ boxes,
                      const int* __restrict__ masks, float* __restrict__ ws,
                      float* rs /*1024*/, float* rw /*1024*/, float* red /*5*/) {
    int bm = unit / PCH;
    int ch = unit % PCH;
    int b = bm / NM, m = bm % NM;
    int pix0 = ch * (HW / PCH);
    float locmax = -INFINITY;
    int tid = threadIdx.x;
    if (m == 0) {
        for (int pix = pix0 + tid; pix < pix0 + HW / PCH; pix += 320) {
            float fwv = ws[OFF_AWRED + b * HW + pix];
            bool fg = (ws[OFF_ASUM + b * HW + pix] != 0.0f);
            ws[OFF_Z + (size_t)bm * HW + pix] = fg ? fwv : FMIN_F;
            locmax = fmaxf(locmax, fwv);
        }
    } else {
        int n = m - 1;
        int msk = masks[b * NN + n];
        if (msk) {
            float x1, y1, bw, bh;
            get_box(boxes, b, n, x1, y1, bw, bh);
            int h0 = pix0 >> 6;
            float ry_lo = ((float)h0 - y1) / bh - 0.5f;
            float ry_hi = ((float)(h0 + 7) - y1) / bh - 0.5f;
            int iy_lo = max(0, (int)floorf(fminf(fmaxf(ry_lo, 0.0f), 31.0f)) - 1);
            int iy_hi = min(31, (int)floorf(fminf(fmaxf(ry_hi, 0.0f), 31.0f)) + 2);
            const float* fsum  = ws + OFF_FSUM + b * HW;
            const float* fwred = ws + OFF_FWRED + b * HW;
            for (int cell = tid; cell < 1024; cell += 320) {
                int q = cell & 31, p = cell >> 5;
                if (p < iy_lo || p > iy_hi) continue;
                float accs = 0.f, accw = 0.f;
#pragma unroll
                for (int di = 0; di < 2; di++) {
#pragma unroll
                    for (int dj = 0; dj < 2; dj++) {
                        float y = y1 + ((float)p + 0.25f + 0.5f * (float)di) * bh;
                        float x = x1 + ((float)q + 0.25f + 0.5f * (float)dj) * bw;
                        float yc = fminf(fmaxf(y, 0.0f), 63.0f);
                        float xc = fminf(fmaxf(x, 0.0f), 63.0f);
                        int iy0 = (int)floorf(yc), ix0 = (int)floorf(xc);
                        int iy1 = min(iy0 + 1, 63), ix1 = min(ix0 + 1, 63);
                        float wy = yc - (float)iy0, wx = xc - (float)ix0;
                        float w00 = (1.f - wy) * (1.f - wx), w01 = (1.f - wy) * wx;
                        float w10 = wy * (1.f - wx), w11 = wy * wx;
                        accs += w00 * fsum[iy0 * 64 + ix0] + w01 * fsum[iy0 * 64 + ix1]
                              + w10 * fsum[iy1 * 64 + ix0] + w11 * fsum[iy1 * 64 + ix1];
                        accw += w00 * fwred[iy0 * 64 + ix0] + w01 * fwred[iy0 * 64 + ix1]
                              + w10 * fwred[iy1 * 64 + ix0] + w11 * fwred[iy1 * 64 + ix1];
                    }
                }
                rs[cell] = accs * 0.25f;
                rw[cell] = accw * 0.25f;
            }
            __syncthreads();
            for (int pix = pix0 + tid; pix < pix0 + HW / PCH; pix += 320) {
                int h = pix >> 6, wp = pix & 63;
                float fwv = 0.0f;
                bool fg = false;
                float ry = ((float)h - y1) / bh - 0.5f;
                float rx = ((float)wp - x1) / bw - 0.5f;
                bool valid = (ry > -1.0f) && (ry < 32.0f) && (rx > -1.0f) && (rx < 32.0f);
                if (valid) {
                    float yc = fminf(fmaxf(ry, 0.0f), 31.0f);
                    float xc = fminf(fmaxf(rx, 0.0f), 31.0f);
                    int iy0 = (int)floorf(yc), ix0 = (int)floorf(xc);
                    int iy1 = min(iy0 + 1, 31), ix1 = min(ix0 + 1, 31);
                    float wy = yc - (float)iy0, wx = xc - (float)ix0;
                    float w00 = (1.f - wy) * (1.f - wx), w01 = (1.f - wy) * wx;
                    float w10 = wy * (1.f - wx), w11 = wy * wx;
                    fwv = w00 * rw[iy0 * 32 + ix0] + w01 * rw[iy0 * 32 + ix1]
                        + w10 * rw[iy1 * 32 + ix0] + w11 * rw[iy1 * 32 + ix1];
                    float su = w00 * rs[iy0 * 32 + ix0] + w01 * rs[iy0 * 32 + ix1]
                             + w10 * rs[iy1 * 32 + ix0] + w11 * rs[iy1 * 32 + ix1];
                    fg = (su != 0.0f);
                }
                ws[OFF_Z + (size_t)bm * HW + pix] = fg ? fwv : FMIN_F;
                locmax = fmaxf(locmax, fwv);
            }
        } else {
            for (int pix = pix0 + tid; pix < pix0 + HW / PCH; pix += 320)
                ws[OFF_Z + (size_t)bm * HW + pix] = FMIN_F;
            locmax = 0.0f;
        }
    }
    // 320-thread max reduction: wave shuffle -> 5 partials -> thread 0
#pragma unroll
    for (int off = 32; off > 0; off >>= 1)
        locmax = fmaxf(locmax, __shfl_down(locmax, off, 64));
    int wid = tid >> 6, lane = tid & 63;
    if (lane == 0) red[wid] = locmax;
    __syncthreads();
    if (tid == 0) {
        float mx = red[0];
#pragma unroll
        for (int k = 1; k < 5; k++) mx = fmaxf(mx, red[k]);
        atomicMax((unsigned*)(ws + OFF_MP) + bm, encf(mx));
    }
}

// Kernel 2: roifeat (blocks [0,7680)) || fw (blocks [7680,7680+496))
__global__ void k_stage2(const unsigned* __restrict__ nbf, const float* __restrict__ boxes,
                         const int* __restrict__ masks, float* __restrict__ ws,
                         unsigned* __restrict__ roif) {
    __shared__ float smem[2048 + 80];
    __shared__ int bsm[8];
    __shared__ float red[5];
    int blk = blockIdx.x;
    if (blk < GRID_ROIF) {
        do_roifeat(blk, nbf, boxes, masks, roif, smem, bsm);
    } else {
        do_fw(blk - GRID_ROIF, boxes, masks, ws, smem, smem + 1024, red);
    }
}

// Kernel 3: fused MLP + per-pixel softmax + final gather with compact
// active-ROI list. block = 8 pixels x 40 lanes; thread = 8 channels.
__global__ void k_final(const float* __restrict__ attn, const float* __restrict__ boxes,
                        const int* __restrict__ perm, const float* __restrict__ w1,
                        const float* __restrict__ b1, const float* __restrict__ w2,
                        const float* __restrict__ b2, const float* __restrict__ ws,
                        const unsigned* __restrict__ roif, float* __restrict__ out) {
    __shared__ float mpg[NM], hb[NM], scal[32], wbuf[8][32];
    __shared__ int acnt[8];
    __shared__ unsigned char alist[8][NN];
    int t = threadIdx.x;
    int idx0 = blockIdx.x * 8;         // all 8 pixels share the same b
    int b = idx0 >> 12;

    if (t < 8) acnt[t] = 0;
    if (t < NM) {
        unsigned e = ((const unsigned*)(ws + OFF_MP))[b * NM + ((t == 0) ? 0 : 1 + perm[t - 1])];
        mpg[t] = decf(e);
    }
    __syncthreads();
    if (t < NM) {
        float a = b1[t];
#pragma unroll
        for (int k = 0; k < NM; k++) a += mpg[k] * w1[k * NM + t];
        hb[t] = fmaxf(a, 0.0f);
    }
    __syncthreads();
    if (t < NM) {
        float a = b2[t];
#pragma unroll
        for (int k = 0; k < NM; k++) a += hb[k] * w2[k * NM + t];
        float sig = 1.0f / (1.0f + expf(-a));
        if (t == 0) scal[0] = sig;
        else        scal[1 + perm[t - 1]] = sig;
    }
    __syncthreads();

    if (t < 256) {
        int pg = t >> 5, m = t & 31;
        int pix = (idx0 + pg) & 4095;
        float zz = FMIN_F;
        if (m < NM) {
            float v = ws[OFF_Z + (size_t)(b * NM + m) * HW + pix];
            zz = (v == FMIN_F) ? FMIN_F : v * scal[m];
        }
        float mx = zz;
#pragma unroll
        for (int off = 16; off > 0; off >>= 1)
            mx = fmaxf(mx, __shfl_xor(mx, off, 64));
        float e = (m < NM) ? expf(zz - mx) : 0.0f;
        float s = e;
#pragma unroll
        for (int off = 16; off > 0; off >>= 1)
            s += __shfl_xor(s, off, 64);
        if (m < NM) {
            float w = e / s;
            wbuf[pg][m] = w;
            if (m >= 1 && w != 0.0f) {
                int pos = atomicAdd(&acnt[pg], 1);
                alist[pg][pos] = (unsigned char)(m - 1);
            }
        }
    }
    __syncthreads();

    int pid = t / 40;
    int v = t - pid * 40;
    int idx = idx0 + pid;
    int pix = idx & 4095;
    int h = pix >> 6, wp = pix & 63;
    float w0 = wbuf[pid][0];
    const float4* at4 = (const float4*)attn;
    float4 a0 = at4[(size_t)idx * 80 + v * 2];
    float4 a1 = at4[(size_t)idx * 80 + v * 2 + 1];
    float4 acc0, acc1;
    acc0.x = a0.x * w0; acc0.y = a0.y * w0; acc0.z = a0.z * w0; acc0.w = a0.w * w0;
    acc1.x = a1.x * w0; acc1.y = a1.y * w0; acc1.z = a1.z * w0; acc1.w = a1.w * w0;
    const uint4* r4 = (const uint4*)roif;
    int na = acnt[pid];
    for (int k = 0; k < na; k++) {
        int n = alist[pid][k];
        float wn = wbuf[pid][n + 1];
        float x1, y1, bw, bh;
        get_box(boxes, b, n, x1, y1, bw, bh);
        float ry = ((float)h - y1) / bh - 0.5f;
        float rx = ((float)wp - x1) / bw - 0.5f;
        float yc = fminf(fmaxf(ry, 0.0f), 31.0f);
        float xc = fminf(fmaxf(rx, 0.0f), 31.0f);
        int iy0 = (int)floorf(yc), ix0 = (int)floorf(xc);
        int iy1 = min(iy0 + 1, 31), ix1 = min(ix0 + 1, 31);
        float wy = yc - (float)iy0, wx = xc - (float)ix0;
        float w00 = (1.f - wy) * (1.f - wx) * wn, w01 = (1.f - wy) * wx * wn;
        float w10 = wy * (1.f - wx) * wn, w11 = wy * wx * wn;
        size_t base = ((size_t)(b * NN + n)) << 10;
        uint4 U00 = r4[(base + iy0 * 32 + ix0) * 40 + v];
        uint4 U01 = r4[(base + iy0 * 32 + ix1) * 40 + v];
        uint4 U10 = r4[(base + iy1 * 32 + ix0) * 40 + v];
        uint4 U11 = r4[(base + iy1 * 32 + ix1) * 40 + v];
        acc0.x += w00 * blo(U00.x) + w01 * blo(U01.x) + w10 * blo(U10.x) + w11 * blo(U11.x);
        acc0.y += w00 * bhi(U00.x) + w01 * bhi(U01.x) + w10 * bhi(U10.x) + w11 * bhi(U11.x);
        acc0.z += w00 * blo(U00.y) + w01 * blo(U01.y) + w10 * blo(U10.y) + w11 * blo(U11.y);
        acc0.w += w00 * bhi(U00.y) + w01 * bhi(U01.y) + w10 * bhi(U10.y) + w11 * bhi(U11.y);
        acc1.x += w00 * blo(U00.z) + w01 * blo(U01.z) + w10 * blo(U10.z) + w11 * blo(U11.z);
        acc1.y += w00 * bhi(U00.z) + w01 * bhi(U01.z) + w10 * bhi(U10.z) + w11 * bhi(U11.z);
        acc1.z += w00 * blo(U00.w) + w01 * blo(U01.w) + w10 * blo(U10.w) + w11 * blo(U11.w);
        acc1.w += w00 * bhi(U00.w) + w01 * bhi(U01.w) + w10 * bhi(U10.w) + w11 * bhi(U11.w);
    }
    nfloat4 nv0 = { acc0.x, acc0.y, acc0.z, acc0.w };
    nfloat4 nv1 = { acc1.x, acc1.y, acc1.z, acc1.w };
    __builtin_nontemporal_store(nv0, ((nfloat4*)out) + (size_t)idx * 80 + v * 2);
    __builtin_nontemporal_store(nv1, ((nfloat4*)out) + (size_t)idx * 80 + v * 2 + 1);
}

extern "C" void kernel_launch(void* const* d_in, const int* in_sizes, int n_in,
                              void* d_out, int out_size, void* d_ws, size_t ws_size,
                              hipStream_t stream) {
    const float* nhs   = (const float*)d_in[0];
    const float* attn  = (const float*)d_in[1];
    const float* boxes = (const float*)d_in[2];
    const int*   masks = (const int*)d_in[3];
    const int*   perm  = (const int*)d_in[4];
    const float* wred  = (const float*)d_in[5];
    const float* w1    = (const float*)d_in[6];
    const float* b1    = (const float*)d_in[7];
    const float* w2    = (const float*)d_in[8];
    const float* b2    = (const float*)d_in[9];
    float* out = (float*)d_out;
    float* ws = (float*)d_ws;
    unsigned* roif = (unsigned*)((char*)d_ws + ROIF_BYTE);
    unsigned* nbf  = (unsigned*)((char*)d_ws + NHSBF_BYTE);

    k_pre<<<GRID_RED, 320, 0, stream>>>(nhs, attn, wred, ws, nbf);
    k_stage2<<<GRID_ROIF + GRID_FW, 320, 0, stream>>>(nbf, boxes, masks, ws, roif);
    k_final<<<NB * HW / 8, 320, 0, stream>>>(attn, boxes, perm, w1, b1, w2, b2, ws, roif, out);
}

// Round 9
// 116.288 us; speedup vs baseline: 1.0290x; 1.0290x over previous
//
#include <hip/hip_runtime.h>
#include <hip/hip_bf16.h>

#define NB 2
#define NN 30
#define NC 320
#define NM 31
#define HW 4096
#define FMIN_F (-3.40282346638528859812e+38f)
#define FCH 4                  // pixel chunks per (b,m) in fwmax

typedef float nfloat4 __attribute__((ext_vector_type(4)));

// workspace layout (float offsets)
#define OFF_ASUM   0         // [2*4096]  sum_c attn
#define OFF_AWRED  8192      // [2*4096]  sum_c attn*w_reduce
#define OFF_RS     16384     // [2*30*1024] per-cell channel-sum of roi_feats (fp32)
#define OFF_RW     77824     // [2*30*1024] per-cell w_reduce-dot of roi_feats (fp32)
#define OFF_MP     139264    // [64] per-(b,m) max of raw fw (monotone-uint encoded)
#define WS_FLOATS  139328
#define ROIF_BYTE  557312    // bf16 roi_feats: 2*30*1024*320*2 = 39321600 B

#define GRID_ROIF (NB * NN * 128)      // 8 cells/block -> 7680
#define GRID_RED  1639                 // ceil(8192/5)

__device__ __forceinline__ void get_box(const float* boxes, int b, int n,
                                        float& x1, float& y1, float& bw, float& bh) {
    const float* p = boxes + (b * NN + n) * 4;
    float X1 = p[0] * 64.0f - 0.5f;
    float Y1 = p[1] * 64.0f - 0.5f;
    float X2 = p[2] * 64.0f - 0.5f;
    float Y2 = p[3] * 64.0f - 0.5f;
    x1 = X1; y1 = Y1;
    bw = (X2 - X1) / 32.0f;
    bh = (Y2 - Y1) / 32.0f;
}

__device__ __forceinline__ unsigned short f2bf(float f) {
    __hip_bfloat16 h = __float2bfloat16(f);
    return *reinterpret_cast<unsigned short*>(&h);
}
__device__ __forceinline__ unsigned pack2(float a, float b) {
    return (unsigned)f2bf(a) | ((unsigned)f2bf(b) << 16);
}
__device__ __forceinline__ float blo(unsigned u) { return __uint_as_float(u << 16); }
__device__ __forceinline__ float bhi(unsigned u) { return __uint_as_float(u & 0xffff0000u); }

// monotone float <-> uint encoding for atomicMax over signed floats
__device__ __forceinline__ unsigned encf(float f) {
    unsigned u = __float_as_uint(f);
    return (u & 0x80000000u) ? ~u : (u | 0x80000000u);
}
__device__ __forceinline__ float decf(unsigned e) {
    unsigned u = (e & 0x80000000u) ? (e & 0x7fffffffu) : ~e;
    return __uint_as_float(u);
}

// ---- stage1 part A: roi_feats gather (fp32 nhs) + per-cell rs/rw reduction ----
// block = 8 cells x 40 lanes; thread = 8 channels.
__device__ void do_roifeat(int blk, const float* __restrict__ nhs,
                           const float* __restrict__ boxes,
                           const int* __restrict__ masks,
                           const float* __restrict__ wred,
                           float* __restrict__ ws,
                           unsigned* __restrict__ roif,
                           float* wsm /*[72]*/, int* bsm /*[8]*/,
                           float* partS /*[320]*/, float* partW /*[320]*/) {
    int bn = blk >> 7;                 // 8 cells/block, 128 blocks per (b,n)
    int n = bn % NN;
    int b = bn / NN;
    if (masks[b * NN + n] == 0) return;
    int tid = threadIdx.x;
    float x1, y1, bw, bh;
    get_box(boxes, b, n, x1, y1, bw, bh);

    if (tid < 8) {
        int cell = blk * 8 + tid;
        int q = cell & 31;
        int p = (cell >> 5) & 31;
        float W[9] = {0.f,0.f,0.f,0.f,0.f,0.f,0.f,0.f,0.f};
        float wys[4], wxs[4];
        int iy0s[4], ix0s[4];
        int iymin = 64, ixmin = 64;
#pragma unroll
        for (int s_ = 0; s_ < 4; s_++) {
            int di = s_ >> 1, dj = s_ & 1;
            float y = y1 + ((float)p + 0.25f + 0.5f * (float)di) * bh;
            float x = x1 + ((float)q + 0.25f + 0.5f * (float)dj) * bw;
            float yc = fminf(fmaxf(y, 0.0f), 63.0f);
            float xc = fminf(fmaxf(x, 0.0f), 63.0f);
            int iy0 = (int)floorf(yc), ix0 = (int)floorf(xc);
            wys[s_] = yc - (float)iy0;
            wxs[s_] = xc - (float)ix0;
            iy0s[s_] = iy0; ix0s[s_] = ix0;
            iymin = min(iymin, iy0); ixmin = min(ixmin, ix0);
        }
#pragma unroll
        for (int s_ = 0; s_ < 4; s_++) {
            float wy = wys[s_], wx = wxs[s_];
            int dy = iy0s[s_] - iymin;
            int dx = ix0s[s_] - ixmin;
            bool yt = (iy0s[s_] == 63);
            bool xt = (ix0s[s_] == 63);
            float ay0 = yt ? 1.0f : (1.0f - wy);
            float ay1 = yt ? 0.0f : wy;
            float ax0 = xt ? 1.0f : (1.0f - wx);
            float ax1 = xt ? 0.0f : wx;
            float r0 = dy ? 0.0f : ay0;
            float r1 = dy ? ay0  : ay1;
            float r2 = dy ? ay1  : 0.0f;
            float c0 = dx ? 0.0f : ax0;
            float c1 = dx ? ax0  : ax1;
            float c2 = dx ? ax1  : 0.0f;
            W[0] += r0 * c0; W[1] += r0 * c1; W[2] += r0 * c2;
            W[3] += r1 * c0; W[4] += r1 * c1; W[5] += r1 * c2;
            W[6] += r2 * c0; W[7] += r2 * c1; W[8] += r2 * c2;
        }
#pragma unroll
        for (int k = 0; k < 9; k++) wsm[tid * 9 + k] = W[k] * 0.25f;
        bsm[tid] = iymin * 64 + ixmin;
    }
    __syncthreads();

    int cid = tid / 40;
    int v = tid - cid * 40;            // 8-channel group
    int cell = blk * 8 + cid;
    const float4* fb4 = (const float4*)(nhs + (size_t)b * HW * NC);
    int base = bsm[cid];
    float4 acc0 = make_float4(0.f, 0.f, 0.f, 0.f);
    float4 acc1 = make_float4(0.f, 0.f, 0.f, 0.f);
#pragma unroll
    for (int i = 0; i < 3; i++) {
#pragma unroll
        for (int j = 0; j < 3; j++) {
            float w = wsm[cid * 9 + i * 3 + j];
            if (w != 0.0f) {
                int off = (base + i * 64 + j) * 80 + v * 2;
                float4 f0 = fb4[off];
                float4 f1 = fb4[off + 1];
                acc0.x += w * f0.x; acc0.y += w * f0.y;
                acc0.z += w * f0.z; acc0.w += w * f0.w;
                acc1.x += w * f1.x; acc1.y += w * f1.y;
                acc1.z += w * f1.z; acc1.w += w * f1.w;
            }
        }
    }
    uint4 pk;
    pk.x = pack2(acc0.x, acc0.y);
    pk.y = pack2(acc0.z, acc0.w);
    pk.z = pack2(acc1.x, acc1.y);
    pk.w = pack2(acc1.z, acc1.w);
    ((uint4*)roif)[(size_t)cell * 40 + v] = pk;

    // per-cell channel reductions (fp32, pre-rounding) -> rs/rw grids
    const float4* w4 = (const float4*)wred;
    float4 wv0 = w4[v * 2];
    float4 wv1 = w4[v * 2 + 1];
    partS[tid] = acc0.x + acc0.y + acc0.z + acc0.w + acc1.x + acc1.y + acc1.z + acc1.w;
    partW[tid] = acc0.x * wv0.x + acc0.y * wv0.y + acc0.z * wv0.z + acc0.w * wv0.w
               + acc1.x * wv1.x + acc1.y * wv1.y + acc1.z * wv1.z + acc1.w * wv1.w;
    __syncthreads();
    if (tid < 8) {
        float ss = 0.f, ww = 0.f;
#pragma unroll 8
        for (int k = 0; k < 40; k++) {
            ss += partS[tid * 40 + k];
            ww += partW[tid * 40 + k];
        }
        int c2 = blk * 8 + tid;
        ws[OFF_RS + c2] = ss;
        ws[OFF_RW + c2] = ww;
    }
}

// ---- stage1 part B: attn channel reductions (one wave per row) ----
__device__ void do_reduce(int rblk, const float* __restrict__ attn,
                          const float* __restrict__ wred, float* __restrict__ ws) {
    if (rblk == 0 && threadIdx.x < 64)
        ((unsigned*)(ws + OFF_MP))[threadIdx.x] = 0u;   // below encf(any float)
    int wave = threadIdx.x >> 6;
    int lane = threadIdx.x & 63;
    int row = rblk * 5 + wave;
    if (row >= NB * HW) return;
    const float4* a4 = (const float4*)(attn + (size_t)row * NC);
    const float4* w4 = (const float4*)wred;
    float4 wv = w4[lane];
    float4 av = a4[lane];
    float s_a = av.x + av.y + av.z + av.w;
    float w_a = av.x * wv.x + av.y * wv.y + av.z * wv.z + av.w * wv.w;
    if (lane < 16) {
        float4 wv2 = w4[lane + 64];
        float4 av2 = a4[lane + 64];
        s_a += av2.x + av2.y + av2.z + av2.w;
        w_a += av2.x * wv2.x + av2.y * wv2.y + av2.z * wv2.z + av2.w * wv2.w;
    }
#pragma unroll
    for (int off = 32; off > 0; off >>= 1) {
        s_a += __shfl_down(s_a, off, 64);
        w_a += __shfl_down(w_a, off, 64);
    }
    if (lane == 0) {
        ws[OFF_ASUM + row]  = s_a;
        ws[OFF_AWRED + row] = w_a;
    }
}

// Kernel 1: roifeat (blocks [0,7680)) || reduce (blocks [7680,7680+1639))
__global__ void k_stage1(const float* __restrict__ nhs, const float* __restrict__ attn,
                         const float* __restrict__ boxes, const int* __restrict__ masks,
                         const float* __restrict__ wred, float* __restrict__ ws,
                         unsigned* __restrict__ roif) {
    __shared__ float wsm[72];
    __shared__ int bsm[8];
    __shared__ float partS[320], partW[320];
    int blk = blockIdx.x;
    if (blk < GRID_ROIF) {
        do_roifeat(blk, nhs, boxes, masks, wred, ws, roif, wsm, bsm, partS, partW);
    } else {
        do_reduce(blk - GRID_ROIF, attn, wred, ws);
    }
}

// Kernel 2: per-(b,m) max of ungated fw over pixels -> MP (atomicMax, encoded).
// block = ((b,m), chunk of 1024 pixels), 256 threads.
__global__ void k_fwmax(const float* __restrict__ boxes, const int* __restrict__ masks,
                        float* __restrict__ ws) {
    int unit = blockIdx.x;
    int bm = unit / FCH, ch = unit % FCH;
    int b = bm / NM, m = bm % NM;
    int pix0 = ch * (HW / FCH);
    int tid = threadIdx.x;
    float locmax = -INFINITY;
    if (m == 0) {
        for (int pix = pix0 + tid; pix < pix0 + HW / FCH; pix += 256)
            locmax = fmaxf(locmax, ws[OFF_AWRED + b * HW + pix]);
    } else {
        int n = m - 1;
        if (masks[b * NN + n]) {
            float x1, y1, bw, bh;
            get_box(boxes, b, n, x1, y1, bw, bh);
            const float* rw = ws + OFF_RW + (b * NN + n) * 1024;
            for (int pix = pix0 + tid; pix < pix0 + HW / FCH; pix += 256) {
                int h = pix >> 6, wp = pix & 63;
                float fwv = 0.0f;
                float ry = ((float)h - y1) / bh - 0.5f;
                float rx = ((float)wp - x1) / bw - 0.5f;
                bool valid = (ry > -1.0f) && (ry < 32.0f) && (rx > -1.0f) && (rx < 32.0f);
                if (valid) {
                    float yc = fminf(fmaxf(ry, 0.0f), 31.0f);
                    float xc = fminf(fmaxf(rx, 0.0f), 31.0f);
                    int iy0 = (int)floorf(yc), ix0 = (int)floorf(xc);
                    int iy1 = min(iy0 + 1, 31), ix1 = min(ix0 + 1, 31);
                    float wy = yc - (float)iy0, wx = xc - (float)ix0;
                    fwv = (1.f - wy) * (1.f - wx) * rw[iy0 * 32 + ix0]
                        + (1.f - wy) * wx * rw[iy0 * 32 + ix1]
                        + wy * (1.f - wx) * rw[iy1 * 32 + ix0]
                        + wy * wx * rw[iy1 * 32 + ix1];
                }
                locmax = fmaxf(locmax, fwv);
            }
        } else {
            locmax = 0.0f;   // masked instance: fw == 0 everywhere
        }
    }
#pragma unroll
    for (int off = 32; off > 0; off >>= 1)
        locmax = fmaxf(locmax, __shfl_down(locmax, off, 64));
    __shared__ float red[4];
    int wid = tid >> 6, lane = tid & 63;
    if (lane == 0) red[wid] = locmax;
    __syncthreads();
    if (tid == 0) {
        float mx = fmaxf(fmaxf(red[0], red[1]), fmaxf(red[2], red[3]));
        atomicMax((unsigned*)(ws + OFF_MP) + bm, encf(mx));
    }
}

// Kernel 3: fused MLP + inline-z softmax + final gather with compact
// active-ROI list. block = 8 pixels x 40 lanes; thread = 8 channels.
__global__ void k_final(const float* __restrict__ attn, const float* __restrict__ boxes,
                        const int* __restrict__ masks, const int* __restrict__ perm,
                        const float* __restrict__ w1, const float* __restrict__ b1,
                        const float* __restrict__ w2, const float* __restrict__ b2,
                        const float* __restrict__ ws, const unsigned* __restrict__ roif,
                        float* __restrict__ out) {
    __shared__ float mpg[NM], hb[NM], scal[32], wbuf[8][32];
    __shared__ int acnt[8];
    __shared__ unsigned char alist[8][NN];
    int t = threadIdx.x;
    int idx0 = blockIdx.x * 8;         // all 8 pixels share the same b
    int b = idx0 >> 12;

    if (t < 8) acnt[t] = 0;
    if (t < NM) {
        unsigned e = ((const unsigned*)(ws + OFF_MP))[b * NM + ((t == 0) ? 0 : 1 + perm[t - 1])];
        mpg[t] = decf(e);
    }
    __syncthreads();
    if (t < NM) {
        float a = b1[t];
#pragma unroll
        for (int k = 0; k < NM; k++) a += mpg[k] * w1[k * NM + t];
        hb[t] = fmaxf(a, 0.0f);
    }
    __syncthreads();
    if (t < NM) {
        float a = b2[t];
#pragma unroll
        for (int k = 0; k < NM; k++) a += hb[k] * w2[k * NM + t];
        float sig = 1.0f / (1.0f + expf(-a));
        if (t == 0) scal[0] = sig;
        else        scal[1 + perm[t - 1]] = sig;
    }
    __syncthreads();

    // softmax with inline z: one thread per (pixel, m)
    if (t < 256) {
        int pg = t >> 5, m = t & 31;
        int pix = (idx0 + pg) & 4095;
        float zz = FMIN_F;
        if (m == 0) {
            float fwv = ws[OFF_AWRED + b * HW + pix];
            bool fg = (ws[OFF_ASUM + b * HW + pix] != 0.0f);
            zz = fg ? fwv * scal[0] : FMIN_F;
        } else if (m < NM) {
            int n = m - 1;
            if (masks[b * NN + n]) {
                float x1, y1, bw, bh;
                get_box(boxes, b, n, x1, y1, bw, bh);
                int h = pix >> 6, wp = pix & 63;
                float ry = ((float)h - y1) / bh - 0.5f;
                float rx = ((float)wp - x1) / bw - 0.5f;
                bool valid = (ry > -1.0f) && (ry < 32.0f) && (rx > -1.0f) && (rx < 32.0f);
                if (valid) {
                    float yc = fminf(fmaxf(ry, 0.0f), 31.0f);
                    float xc = fminf(fmaxf(rx, 0.0f), 31.0f);
                    int iy0 = (int)floorf(yc), ix0 = (int)floorf(xc);
                    int iy1 = min(iy0 + 1, 31), ix1 = min(ix0 + 1, 31);
                    float wy = yc - (float)iy0, wx = xc - (float)ix0;
                    float w00 = (1.f - wy) * (1.f - wx), w01 = (1.f - wy) * wx;
                    float w10 = wy * (1.f - wx), w11 = wy * wx;
                    const float* rw = ws + OFF_RW + (b * NN + n) * 1024;
                    const float* rs = ws + OFF_RS + (b * NN + n) * 1024;
                    float fwv = w00 * rw[iy0 * 32 + ix0] + w01 * rw[iy0 * 32 + ix1]
                              + w10 * rw[iy1 * 32 + ix0] + w11 * rw[iy1 * 32 + ix1];
                    float su  = w00 * rs[iy0 * 32 + ix0] + w01 * rs[iy0 * 32 + ix1]
                              + w10 * rs[iy1 * 32 + ix0] + w11 * rs[iy1 * 32 + ix1];
                    if (su != 0.0f) zz = fwv * scal[m];
                }
            }
        }
        float mx = zz;
#pragma unroll
        for (int off = 16; off > 0; off >>= 1)
            mx = fmaxf(mx, __shfl_xor(mx, off, 64));
        float e = (m < NM) ? expf(zz - mx) : 0.0f;
        float s = e;
#pragma unroll
        for (int off = 16; off > 0; off >>= 1)
            s += __shfl_xor(s, off, 64);
        if (m < NM) {
            float w = e / s;
            wbuf[pg][m] = w;
            if (m >= 1 && w != 0.0f) {
                int pos = atomicAdd(&acnt[pg], 1);
                alist[pg][pos] = (unsigned char)(m - 1);
            }
        }
    }
    __syncthreads();

    int pid = t / 40;
    int v = t - pid * 40;
    int idx = idx0 + pid;
    int pix = idx & 4095;
    int h = pix >> 6, wp = pix & 63;
    float w0 = wbuf[pid][0];
    const float4* at4 = (const float4*)attn;
    float4 a0 = at4[(size_t)idx * 80 + v * 2];
    float4 a1 = at4[(size_t)idx * 80 + v * 2 + 1];
    float4 acc0, acc1;
    acc0.x = a0.x * w0; acc0.y = a0.y * w0; acc0.z = a0.z * w0; acc0.w = a0.w * w0;
    acc1.x = a1.x * w0; acc1.y = a1.y * w0; acc1.z = a1.z * w0; acc1.w = a1.w * w0;
    const uint4* r4 = (const uint4*)roif;
    int na = acnt[pid];
    for (int k = 0; k < na; k++) {
        int n = alist[pid][k];
        float wn = wbuf[pid][n + 1];
        float x1, y1, bw, bh;
        get_box(boxes, b, n, x1, y1, bw, bh);
        float ry = ((float)h - y1) / bh - 0.5f;
        float rx = ((float)wp - x1) / bw - 0.5f;
        float yc = fminf(fmaxf(ry, 0.0f), 31.0f);
        float xc = fminf(fmaxf(rx, 0.0f), 31.0f);
        int iy0 = (int)floorf(yc), ix0 = (int)floorf(xc);
        int iy1 = min(iy0 + 1, 31), ix1 = min(ix0 + 1, 31);
        float wy = yc - (float)iy0, wx = xc - (float)ix0;
        float w00 = (1.f - wy) * (1.f - wx) * wn, w01 = (1.f - wy) * wx * wn;
        float w10 = wy * (1.f - wx) * wn, w11 = wy * wx * wn;
        size_t base = ((size_t)(b * NN + n)) << 10;
        uint4 U00 = r4[(base + iy0 * 32 + ix0) * 40 + v];
        uint4 U01 = r4[(base + iy0 * 32 + ix1) * 40 + v];
        uint4 U10 = r4[(base + iy1 * 32 + ix0) * 40 + v];
        uint4 U11 = r4[(base + iy1 * 32 + ix1) * 40 + v];
        acc0.x += w00 * blo(U00.x) + w01 * blo(U01.x) + w10 * blo(U10.x) + w11 * blo(U11.x);
        acc0.y += w00 * bhi(U00.x) + w01 * bhi(U01.x) + w10 * bhi(U10.x) + w11 * bhi(U11.x);
        acc0.z += w00 * blo(U00.y) + w01 * blo(U01.y) + w10 * blo(U10.y) + w11 * blo(U11.y);
        acc0.w += w00 * bhi(U00.y) + w01 * bhi(U01.y) + w10 * bhi(U10.y) + w11 * bhi(U11.y);
        acc1.x += w00 * blo(U00.z) + w01 * blo(U01.z) + w10 * blo(U10.z) + w11 * blo(U11.z);
        acc1.y += w00 * bhi(U00.z) + w01 * bhi(U01.z) + w10 * bhi(U10.z) + w11 * bhi(U11.z);
        acc1.z += w00 * blo(U00.w) + w01 * blo(U01.w) + w10 * blo(U10.w) + w11 * blo(U11.w);
        acc1.w += w00 * bhi(U00.w) + w01 * bhi(U01.w) + w10 * bhi(U10.w) + w11 * bhi(U11.w);
    }
    nfloat4 nv0 = { acc0.x, acc0.y, acc0.z, acc0.w };
    nfloat4 nv1 = { acc1.x, acc1.y, acc1.z, acc1.w };
    __builtin_nontemporal_store(nv0, ((nfloat4*)out) + (size_t)idx * 80 + v * 2);
    __builtin_nontemporal_store(nv1, ((nfloat4*)out) + (size_t)idx * 80 + v * 2 + 1);
}

extern "C" void kernel_launch(void* const* d_in, const int* in_sizes, int n_in,
                              void* d_out, int out_size, void* d_ws, size_t ws_size,
                              hipStream_t stream) {
    const float* nhs   = (const float*)d_in[0];
    const float* attn  = (const float*)d_in[1];
    const float* boxes = (const float*)d_in[2];
    const int*   masks = (const int*)d_in[3];
    const int*   perm  = (const int*)d_in[4];
    const float* wred  = (const float*)d_in[5];
    const float* w1    = (const float*)d_in[6];
    const float* b1    = (const float*)d_in[7];
    const float* w2    = (const float*)d_in[8];
    const float* b2    = (const float*)d_in[9];
    float* out = (float*)d_out;
    float* ws = (float*)d_ws;
    unsigned* roif = (unsigned*)((char*)d_ws + ROIF_BYTE);

    k_stage1<<<GRID_ROIF + GRID_RED, 320, 0, stream>>>(nhs, attn, boxes, masks, wred, ws, roif);
    k_fwmax<<<NB * NM * FCH, 256, 0, stream>>>(boxes, masks, ws);
    k_final<<<NB * HW / 8, 320, 0, stream>>>(attn, boxes, masks, perm, w1, b1, w2, b2, ws, roif, out);
}